// Round 10
// baseline (203.986 us; speedup 1.0000x reference)
//
#include <hip/hip_runtime.h>
#include <cstddef>
#include <cstdint>

#define BATCH 16
#define NFULL 896   // 512 real + 384 pad
#define NREAL 512
#define NPAD  384
#define DIM   256

typedef short bf16x8 __attribute__((ext_vector_type(8)));
typedef short s16x4  __attribute__((ext_vector_type(4)));
typedef float f32x4  __attribute__((ext_vector_type(4)));

// round-to-nearest-even f32 -> bf16 bits (no NaN inputs here)
static __device__ inline short f2bf(float v) {
    unsigned u = __float_as_uint(v);
    unsigned r = (u + 0x7FFFu + ((u >> 16) & 1u)) >> 16;
    return (short)r;
}
static __device__ inline float bf2f(short s) {
    return __uint_as_float(((unsigned)(unsigned short)s) << 16);
}

// async global->LDS, 16B per lane. LDS dest = wave-uniform base + lane*16.
static __device__ __forceinline__ void gload_lds16(const void* g, size_t lds_byte_off,
                                                   void* lds_base) {
    __builtin_amdgcn_global_load_lds(
        (const __attribute__((address_space(1))) unsigned int*)(size_t)g,
        (__attribute__((address_space(3))) unsigned int*)(unsigned int)
            ((size_t)lds_base + lds_byte_off),
        16, 0, 0);
}

// ---------------------------------------------------------------------------
// One wave per row: norm, inv-norm, split-bf16 (hi|lo) planes of normalized row.
// Also zero-inits rowsum/colsum, out[0..1], and the batch-barrier counters.
__global__ __launch_bounds__(256) void norm_cvt_kernel(
    const float* __restrict__ x1, const float* __restrict__ x3,
    const float* __restrict__ x2, const float* __restrict__ x4,
    short* __restrict__ A1s, short* __restrict__ B2s,
    float* __restrict__ invn1, float* __restrict__ invn2,
    float* __restrict__ n1, float* __restrict__ n2,
    float* __restrict__ zero_base, float* __restrict__ out,
    int* __restrict__ flags)
{
    const int t = threadIdx.x;
    const int gid = blockIdx.x * 256 + t;
    if (gid < 2 * BATCH * NFULL) zero_base[gid] = 0.f;   // rowsum+colsum contiguous
    if (gid < 2) out[gid] = 0.f;
    if (flags && gid < BATCH * 64) flags[gid] = 0;

    const int w = t >> 6, lane = t & 63;
    const int rg = blockIdx.x * 4 + w;           // 0 .. 2*B*NFULL-1
    const int side = rg >= BATCH * NFULL;
    const int rem  = rg - (side ? BATCH * NFULL : 0);
    const int b = rem / NFULL, row = rem % NFULL;
    const float* src;
    if (!side) src = (row < NREAL) ? x1 + ((size_t)b * NREAL + row) * DIM
                                   : x3 + ((size_t)b * NPAD + (row - NREAL)) * DIM;
    else       src = (row < NREAL) ? x2 + ((size_t)b * NREAL + row) * DIM
                                   : x4 + ((size_t)b * NPAD + (row - NREAL)) * DIM;
    const f32x4 v = ((const f32x4*)src)[lane];
    float ss = v[0]*v[0] + v[1]*v[1] + v[2]*v[2] + v[3]*v[3];
    #pragma unroll
    for (int m = 1; m < 64; m <<= 1) ss += __shfl_xor(ss, m);
    const float nrm = sqrtf(ss);
    const float inv = 1.0f / fmaxf(nrm, 1e-12f);
    if (lane == 0) {
        (side ? invn2 : invn1)[b * NFULL + row] = inv;
        (side ? n2 : n1)[b * NFULL + row] = nrm;
    }
    s16x4 hi, lo;
    #pragma unroll
    for (int c = 0; c < 4; ++c) {
        const float val = v[c] * inv;
        hi[c] = f2bf(val);
        lo[c] = f2bf(val - bf2f(hi[c]));
    }
    short* dst = (side ? B2s : A1s) + ((size_t)b * NFULL + row) * 512;
    *(s16x4*)(dst + lane * 4) = hi;
    *(s16x4*)(dst + 256 + lane * 4) = lo;
}

// ---------------------------------------------------------------------------
// MFMA gram via split-bf16 K=768 (hi*hi + lo*hi + hi*lo), XCD-swizzled grid,
// global_load_lds staging with both-sides XOR swizzle. (Verified R5-R7.)
__global__ __launch_bounds__(256) void gram_mfma_kernel(
    const short* __restrict__ A1s, const short* __restrict__ B2s,
    const float* __restrict__ n1, const float* __restrict__ n2,
    float* __restrict__ S, float* __restrict__ rowsum, float* __restrict__ colsum,
    float* __restrict__ out_hinge)
{
    const int flat = blockIdx.x;                  // 784 = 8 XCD * 98
    const int id = (flat & 7) * 98 + (flat >> 3); // XCD k owns batches {2k,2k+1}
    const int b  = id / 49;
    const int r49 = id % 49;
    const int by = r49 / 7, bx = r49 % 7;
    const int i0 = by * 128;
    const int j0 = bx * 128;
    __shared__ __align__(16) short As[128][64];   // linear: row*128B
    __shared__ __align__(16) short Bs[128][64];
    const int t = threadIdx.x;
    const int wid = t >> 6, lane = t & 63;
    const int wr = wid >> 1, wc = wid & 1;        // 2x2 waves, 64x64 each
    const int lr = lane & 15, lg = lane >> 4;
    f32x4 acc[4][4] = {};

    const short* gA = A1s + ((size_t)b * NFULL + i0) * 512;
    const short* gB = B2s + ((size_t)b * NFULL + j0) * 512;

    int srow[4], scl[4];
    #pragma unroll
    for (int p = 0; p < 4; ++p) {
        const int s = p * 256 + t;
        srow[p] = s >> 3;
        scl[p] = (s & 7) ^ (srow[p] & 7);
    }

    for (int step = 0; step < 12; ++step) {       // K' = 768, BK = 64
        const int kb   = step * 64;
        const int koff = kb & 255;
        const int aoff = (((kb >> 8) == 1) ? 256 : 0) + koff;  // pass1 uses A-lo
        const int boff = (((kb >> 8) == 2) ? 256 : 0) + koff;  // pass2 uses B-lo
        __syncthreads();
        #pragma unroll
        for (int p = 0; p < 4; ++p)
            gload_lds16(gA + (size_t)srow[p] * 512 + aoff + scl[p] * 8,
                        (size_t)(p * 256 + wid * 64) * 16, &As[0][0]);
        #pragma unroll
        for (int p = 0; p < 4; ++p)
            gload_lds16(gB + (size_t)srow[p] * 512 + boff + scl[p] * 8,
                        (size_t)(p * 256 + wid * 64) * 16, &Bs[0][0]);
        __syncthreads();
        #pragma unroll
        for (int kk = 0; kk < 2; ++kk) {
            bf16x8 af[4], bg[4];
            #pragma unroll
            for (int m = 0; m < 4; ++m) {
                const int row = wr * 64 + m * 16 + lr;
                af[m] = *(const bf16x8*)((const char*)&As[0][0]
                         + row * 128 + (((kk * 4 + lg) ^ (row & 7)) << 4));
            }
            #pragma unroll
            for (int n = 0; n < 4; ++n) {
                const int row = wc * 64 + n * 16 + lr;
                bg[n] = *(const bf16x8*)((const char*)&Bs[0][0]
                         + row * 128 + (((kk * 4 + lg) ^ (row & 7)) << 4));
            }
            #pragma unroll
            for (int m = 0; m < 4; ++m)
                #pragma unroll
                for (int n = 0; n < 4; ++n)
                    acc[m][n] = __builtin_amdgcn_mfma_f32_16x16x32_bf16(
                        af[m], bg[n], acc[m][n], 0, 0, 0);
        }
    }

    const bool storeS = (by < 4) && (bx < 4);
    const bool hingeB = (by >= 4) && (bx >= 4);
    float rp[4][4] = {};
    float cp[4] = {};
    float hp = 0.f;
    #pragma unroll
    for (int m = 0; m < 4; ++m) {
        const int row0 = i0 + wr * 64 + m * 16 + lg * 4;
        float n1v[4] = {0.f, 0.f, 0.f, 0.f};
        if (hingeB) {
            #pragma unroll
            for (int r = 0; r < 4; ++r) n1v[r] = n1[b * NFULL + row0 + r];
        }
        #pragma unroll
        for (int n = 0; n < 4; ++n) {
            const int col = j0 + wc * 64 + n * 16 + lr;
            const f32x4 f = acc[m][n];
            float cn = 0.f;
            float sv[4];
            #pragma unroll
            for (int r = 0; r < 4; ++r) {
                sv[r] = __expf(10.f * f[r]);
                rp[m][r] += sv[r];
                cn += sv[r];
            }
            cp[n] += cn;
            if (storeS) {
                #pragma unroll
                for (int r = 0; r < 4; ++r)
                    S[((size_t)b * NREAL + row0 + r) * NREAL + col] = sv[r];
            }
            if (hingeB) {
                const float nn2 = n2[b * NFULL + col];
                #pragma unroll
                for (int r = 0; r < 4; ++r)
                    hp += fmaxf(0.1f - f[r] * n1v[r] * nn2, 0.f);
            }
        }
    }
    if (by < 4) {
        #pragma unroll
        for (int m = 0; m < 4; ++m)
            #pragma unroll
            for (int r = 0; r < 4; ++r) {
                float v = rp[m][r];
                v += __shfl_xor(v, 1); v += __shfl_xor(v, 2);
                v += __shfl_xor(v, 4); v += __shfl_xor(v, 8);
                if (lr == 0)
                    atomicAdd(&rowsum[b * NFULL + i0 + wr * 64 + m * 16 + lg * 4 + r], v);
            }
    }
    if (bx < 4) {
        #pragma unroll
        for (int n = 0; n < 4; ++n) {
            float v = cp[n];
            v += __shfl_xor(v, 16); v += __shfl_xor(v, 32);
            if (lg == 0)
                atomicAdd(&colsum[b * NFULL + j0 + wc * 64 + n * 16 + lr], v);
        }
    }
    if (hingeB) {
        #pragma unroll
        for (int m = 1; m < 64; m <<= 1) hp += __shfl_xor(hp, m);
        if (lane == 0) atomicAdd(out_hinge, hp);
    }
}

// ---------------------------------------------------------------------------
// Per-batch 32-block barrier. R7 lesson: an agent-scope ACQUIRE in the spin
// loop emits an L1/L2 invalidate on EVERY poll (cross-XCD coherence point is
// the MALL) -> invalidation storm, ~10us/barrier. Fix: release-add, RELAXED
// spin (performed at coherence point, fresh, no cache ops), then ONE acquire
// fence after exit. Fence-based synchronization: relaxed read of the released
// value + acquire fence establishes happens-before. Placement-independent.
static __device__ __forceinline__ void batch_barrier(int* cnt, int target) {
    __syncthreads();
    if (threadIdx.x == 0) {
        __hip_atomic_fetch_add(cnt, 1, __ATOMIC_RELEASE, __HIP_MEMORY_SCOPE_AGENT);
        while (__hip_atomic_load(cnt, __ATOMIC_RELAXED,
                                 __HIP_MEMORY_SCOPE_AGENT) < target)
            __builtin_amdgcn_s_sleep(2);
    }
    __syncthreads();
    __builtin_amdgcn_fence(__ATOMIC_ACQUIRE, "agent");   // one-shot invalidate
}

// Softmin of 4 rows held in registers: res[r] = -eps*LSE_j(h_j - A[r][j]*inv_eps).
// All lanes receive the result.
static __device__ __forceinline__ f32x4 softmin_regs(
    const f32x4* A0, const f32x4* A1, f32x4 h0, f32x4 h1,
    float eps, float inv_eps)
{
    f32x4 res;
    #pragma unroll
    for (int rr = 0; rr < 4; ++rr) {
        const f32x4 v0 = h0 - A0[rr] * inv_eps;
        const f32x4 v1 = h1 - A1[rr] * inv_eps;
        float mx = fmaxf(fmaxf(fmaxf(v0[0], v0[1]), fmaxf(v0[2], v0[3])),
                         fmaxf(fmaxf(v1[0], v1[1]), fmaxf(v1[2], v1[3])));
        #pragma unroll
        for (int off = 1; off < 64; off <<= 1) mx = fmaxf(mx, __shfl_xor(mx, off));
        float s = 0.f;
        #pragma unroll
        for (int c = 0; c < 4; ++c) s += __expf(v0[c] - mx);
        #pragma unroll
        for (int c = 0; c < 4; ++c) s += __expf(v1[c] - mx);
        #pragma unroll
        for (int off = 1; off < 64; off <<= 1) s += __shfl_xor(s, off);
        res[rr] = -eps * (mx + __logf(s));
    }
    return res;
}

// ---------------------------------------------------------------------------
// Fused Sinkhorn, register-resident cost matrix.
// 512 blocks x 4 waves; batch b = 2*(id&7) + (id>>3 >= 32) -> XCD-local.
// Each wave owns 4 f-rows (C) + 4 g-rows (CT), transform folded into load.
// Phases: P0 raw transpose S->ST; P1 reg-load + init; P2..P9 iterations;
// P10 final extrapolation + reduce. Per-phase traffic = potentials only.
__global__ __launch_bounds__(256, 2) void sinkhorn_fused_kernel(
    const float* __restrict__ S, float* __restrict__ ST,
    const float* __restrict__ rowsum, const float* __restrict__ colsum,
    float* __restrict__ fs, float* __restrict__ gs, float* __restrict__ out,
    int* __restrict__ flags)
{
    const int id = blockIdx.x;                   // 0..511
    const int xcd = id & 7, slot = id >> 3;      // slot 0..63
    const int b = 2 * xcd + (slot >> 5);
    const int r32 = slot & 31;
    int* cnt = flags + b * 64;                   // 256B-strided counters
    const int t = threadIdx.x;
    const int w = t >> 6, lane = t & 63;
    int phase = 0;
    __shared__ float tile[64][65];
    __shared__ float sred[4];

    // ---- P0: raw transpose S -> ST (2 of the batch's 64 64x64 tiles)
    {
        const int lj = t & 63, r4 = t >> 6;
        #pragma unroll
        for (int q = 0; q < 2; ++q) {
            const int t64 = r32 * 2 + q;
            const int i0 = (t64 >> 3) * 64, j0 = (t64 & 7) * 64;
            __syncthreads();
            #pragma unroll
            for (int rr = 0; rr < 64; rr += 4) {
                const int li = rr + r4;
                tile[li][lj] = S[((size_t)(b * NREAL + i0 + li)) * NREAL + j0 + lj];
            }
            __syncthreads();
            #pragma unroll
            for (int rr = 0; rr < 64; rr += 4) {
                const int lc = rr + r4;
                ST[((size_t)(b * NREAL + j0 + lc)) * NREAL + i0 + lj] = tile[lj][lc];
            }
        }
    }
    batch_barrier(cnt, 32 * ++phase);

    // ---- P1: load cost rows into registers (transform folded in)
    const int wv = r32 * 4 + w;                  // 0..127
    const int ib = wv * 4;                       // wave's first row (both sides)
    f32x4 FA0[4], FA1[4], GA0[4], GA1[4];
    {
        const f32x4 csl0 = *(const f32x4*)(colsum + b * NFULL + 4 * lane);
        const f32x4 csl1 = *(const f32x4*)(colsum + b * NFULL + 256 + 4 * lane);
        const f32x4 rsl0 = *(const f32x4*)(rowsum + b * NFULL + 4 * lane);
        const f32x4 rsl1 = *(const f32x4*)(rowsum + b * NFULL + 256 + 4 * lane);
        #pragma unroll
        for (int rr = 0; rr < 4; ++rr) {
            const float rs = rowsum[b * NFULL + ib + rr];
            const f32x4* M4 = (const f32x4*)(S + ((size_t)(b * NREAL + ib + rr)) * NREAL);
            const f32x4 s0 = M4[lane], s1 = M4[64 + lane];
            #pragma unroll
            for (int c = 0; c < 4; ++c) {
                FA0[rr][c] = 1.0f - s0[c] / (rs + csl0[c] - s0[c]);
                FA1[rr][c] = 1.0f - s1[c] / (rs + csl1[c] - s1[c]);
            }
            const float cs = colsum[b * NFULL + ib + rr];
            const f32x4* T4 = (const f32x4*)(ST + ((size_t)(b * NREAL + ib + rr)) * NREAL);
            const f32x4 u0 = T4[lane], u1 = T4[64 + lane];
            #pragma unroll
            for (int c = 0; c < 4; ++c) {
                GA0[rr][c] = 1.0f - u0[c] / (rsl0[c] + cs - u0[c]);
                GA1[rr][c] = 1.0f - u1[c] / (rsl1[c] + cs - u1[c]);
            }
        }
    }

    float* f0 = fs;  float* g0 = gs;
    float* f1 = fs + BATCH * NREAL;
    float* g1 = gs + BATCH * NREAL;

    // init: f = softmin(9, C, 0); g = softmin(9, CT, 0)
    {
        const f32x4 z = {0.f, 0.f, 0.f, 0.f};
        const f32x4 rf = softmin_regs(FA0, FA1, z, z, 9.0f, 1.0f / 9.0f);
        if (lane == 0) *(f32x4*)(f0 + b * NREAL + ib) = rf;
        const f32x4 rg = softmin_regs(GA0, GA1, z, z, 9.0f, 1.0f / 9.0f);
        if (lane == 0) *(f32x4*)(g0 + b * NREAL + ib) = rg;
    }
    batch_barrier(cnt, 32 * ++phase);

    // ---- P2..P9: 8 averaged symmetric iterations (ping-pong)
    const float epsl[8] = {9.0f, 9.0f, 2.25f, 0.5625f, 0.140625f,
                           0.03515625f, 0.0087890625f, 0.0025f};
    float* fc = f0; float* gc = g0; float* fa = f1; float* ga = g1;
    #pragma unroll
    for (int k = 0; k < 8; ++k) {
        const float eps = epsl[k];
        const float inv_eps = 1.0f / eps;
        const f32x4* gh4 = (const f32x4*)(gc + b * NREAL);
        const f32x4 gh0 = gh4[lane] * inv_eps, gh1 = gh4[64 + lane] * inv_eps;
        const f32x4* fh4 = (const f32x4*)(fc + b * NREAL);
        const f32x4 fh0 = fh4[lane] * inv_eps, fh1 = fh4[64 + lane] * inv_eps;
        const f32x4 rf = softmin_regs(FA0, FA1, gh0, gh1, eps, inv_eps);
        if (lane == 0) {
            const f32x4 fi = *(const f32x4*)(fc + b * NREAL + ib);
            *(f32x4*)(fa + b * NREAL + ib) = 0.5f * (fi + rf);
        }
        const f32x4 rg = softmin_regs(GA0, GA1, fh0, fh1, eps, inv_eps);
        if (lane == 0) {
            const f32x4 gi = *(const f32x4*)(gc + b * NREAL + ib);
            *(f32x4*)(ga + b * NREAL + ib) = 0.5f * (gi + rg);
        }
        batch_barrier(cnt, 32 * ++phase);
        float* tf = fc; fc = fa; fa = tf;
        float* tg = gc; gc = ga; ga = tg;
    }

    // ---- P10: final extrapolation at eps = blur^2; scon into out[1]
    {
        const float eps = 0.0025f, inv_eps = 400.0f;
        const f32x4* gh4 = (const f32x4*)(gc + b * NREAL);
        const f32x4 gh0 = gh4[lane] * inv_eps, gh1 = gh4[64 + lane] * inv_eps;
        const f32x4* fh4 = (const f32x4*)(fc + b * NREAL);
        const f32x4 fh0 = fh4[lane] * inv_eps, fh1 = fh4[64 + lane] * inv_eps;
        const f32x4 rf = softmin_regs(FA0, FA1, gh0, gh1, eps, inv_eps);
        const f32x4 rg = softmin_regs(GA0, GA1, fh0, fh1, eps, inv_eps);
        const float accr = rf[0] + rf[1] + rf[2] + rf[3]
                         + rg[0] + rg[1] + rg[2] + rg[3];
        if (lane == 0) sred[w] = accr;
        __syncthreads();
        if (t == 0)
            atomicAdd(out + 1, (sred[0] + sred[1] + sred[2] + sred[3])
                               * (1.0f / BATCH));
    }
}

// ---------------------------------------------------------------------------
// Non-coop fallbacks (cost + per-phase softmin), and fp32 path for tiny ws.
__global__ __launch_bounds__(256) void cost_kernel(
    float* __restrict__ C, float* __restrict__ CT,
    const float* __restrict__ rowsum, const float* __restrict__ colsum)
{
    const int b  = blockIdx.z;
    const int i0 = blockIdx.y * 64, j0 = blockIdx.x * 64;
    __shared__ float tile[64][65];
    const int t = threadIdx.x;
    const int lj = t & 63, r4 = t >> 6;
    #pragma unroll
    for (int rr = 0; rr < 64; rr += 4) {
        const int li = rr + r4;
        const size_t idx = ((size_t)b * NREAL + i0 + li) * NREAL + j0 + lj;
        const float s  = C[idx];
        const float c = 1.0f - s / (rowsum[b * NFULL + i0 + li]
                                    + colsum[b * NFULL + j0 + lj] - s);
        C[idx] = c;
        tile[li][lj] = c;
    }
    if (CT == nullptr) return;
    __syncthreads();
    #pragma unroll
    for (int rr = 0; rr < 64; rr += 4) {
        const int lc = rr + r4;
        CT[((size_t)b * NREAL + j0 + lc) * NREAL + i0 + lj] = tile[lj][lc];
    }
}

__global__ __launch_bounds__(256) void softmin_kernel(
    const float* __restrict__ C, const float* __restrict__ CT,
    const float* __restrict__ f_in, const float* __restrict__ g_in,
    float* __restrict__ f_out, float* __restrict__ g_out,
    float eps, int mode, float* __restrict__ out)
{
    const int w = threadIdx.x >> 6, lane = threadIdx.x & 63;
    const int rg = blockIdx.x * 4 + w;
    const int side = rg >= 2048;
    const int rem  = side ? rg - 2048 : rg;
    const int b  = rem >> 7;
    const int ib = (rem & 127) * 4;
    const float inv_eps = 1.0f / eps;
    const float* h_src = (side ? f_in : g_in) + b * NREAL;

    f32x4 h0 = {0.f, 0.f, 0.f, 0.f}, h1 = h0;
    if (mode != 0) {
        const f32x4* h4 = (const f32x4*)h_src;
        h0 = h4[lane] * inv_eps;
        h1 = h4[64 + lane] * inv_eps;
    }
    const float* Mb;
    size_t stride;
    if (!side)   { Mb = C  + ((size_t)(b * NREAL + ib)) * NREAL; stride = 1; }
    else if (CT) { Mb = CT + ((size_t)(b * NREAL + ib)) * NREAL; stride = 1; }
    else         { Mb = C + (size_t)b * NREAL * NREAL + ib;      stride = NREAL; }

    float res[4];
    float acc_res = 0.f;
    #pragma unroll
    for (int rr = 0; rr < 4; ++rr) {
        float v[8];
        if (stride == 1) {
            const f32x4* M4 = (const f32x4*)(Mb + (size_t)rr * NREAL);
            const f32x4 a0 = M4[lane], a1 = M4[64 + lane];
            #pragma unroll
            for (int c = 0; c < 4; ++c) { v[c] = h0[c] - a0[c] * inv_eps;
                                          v[4+c] = h1[c] - a1[c] * inv_eps; }
        } else {
            const float* M = Mb + rr;
            #pragma unroll
            for (int q = 0; q < 8; ++q) {
                const int j = (q >> 2) * 256 + lane * 4 + (q & 3);
                v[q] = ((q < 4) ? h0[q & 3] : h1[q & 3]) - M[(size_t)j * NREAL] * inv_eps;
            }
        }
        float mx = v[0];
        #pragma unroll
        for (int q = 1; q < 8; ++q) mx = fmaxf(mx, v[q]);
        #pragma unroll
        for (int off = 1; off < 64; off <<= 1) mx = fmaxf(mx, __shfl_xor(mx, off));
        float s = 0.f;
        #pragma unroll
        for (int q = 0; q < 8; ++q) s += __expf(v[q] - mx);
        #pragma unroll
        for (int off = 1; off < 64; off <<= 1) s += __shfl_xor(s, off);
        res[rr] = -eps * (mx + __logf(s));
        acc_res += res[rr];
    }
    if (mode == 2) {
        __shared__ float sred[4];
        if (lane == 0) sred[w] = acc_res;
        __syncthreads();
        if (threadIdx.x == 0)
            atomicAdd(out, (sred[0] + sred[1] + sred[2] + sred[3]) * (1.0f / BATCH));
    } else if (lane == 0) {
        float* st = (side ? g_out : f_out) + b * NREAL + ib;
        if (mode == 0) {
            *(f32x4*)st = f32x4{res[0], res[1], res[2], res[3]};
        } else {
            const f32x4 si = *(const f32x4*)((side ? g_in : f_in) + b * NREAL + ib);
            *(f32x4*)st = 0.5f * (si + f32x4{res[0], res[1], res[2], res[3]});
        }
    }
}

__global__ __launch_bounds__(256) void norm_kernel(
    const float* __restrict__ x1, const float* __restrict__ x3,
    const float* __restrict__ x2, const float* __restrict__ x4,
    float* __restrict__ invn1, float* __restrict__ invn2)
{
    const int w = threadIdx.x >> 6, lane = threadIdx.x & 63;
    const int rg = blockIdx.x * 4 + w;
    const int side = rg / (BATCH * NFULL);
    const int rem  = rg - side * (BATCH * NFULL);
    const int b = rem / NFULL, r = rem % NFULL;
    const float* src;
    if (side == 0)
        src = (r < NREAL) ? x1 + ((size_t)b * NREAL + r) * DIM
                          : x3 + ((size_t)b * NPAD + (r - NREAL)) * DIM;
    else
        src = (r < NREAL) ? x2 + ((size_t)b * NREAL + r) * DIM
                          : x4 + ((size_t)b * NPAD + (r - NREAL)) * DIM;
    float4 v = ((const float4*)src)[lane];
    float ss = v.x*v.x + v.y*v.y + v.z*v.z + v.w*v.w;
    #pragma unroll
    for (int m = 1; m < 64; m <<= 1) ss += __shfl_xor(ss, m);
    if (lane == 0)
        (side == 0 ? invn1 : invn2)[b * NFULL + r] = 1.0f / fmaxf(sqrtf(ss), 1e-12f);
}

__global__ __launch_bounds__(256) void gram_kernel(
    const float* __restrict__ x1, const float* __restrict__ x3,
    const float* __restrict__ x2, const float* __restrict__ x4,
    const float* __restrict__ invn1, const float* __restrict__ invn2,
    float* __restrict__ S, float* __restrict__ rowsum, float* __restrict__ colsum)
{
    const int b  = blockIdx.z;
    const int i0 = blockIdx.y * 64;
    const int j0 = blockIdx.x * 64;
    __shared__ float As[64][68];
    __shared__ float Bs[64][68];
    __shared__ float rsh[64], csh[64];
    const int t = threadIdx.x;
    const int tx = t & 15, ty = t >> 4;
    if (t < 64) { rsh[t] = 0.f; csh[t] = 0.f; }
    float acc[4][4] = {};
    const int lk = t & 63, r4 = t >> 6;
    for (int kc = 0; kc < DIM; kc += 64) {
        __syncthreads();
        #pragma unroll
        for (int rr = 0; rr < 64; rr += 4) {
            const int r = rr + r4;
            const int gi = i0 + r;
            const float* pa = (gi < NREAL) ? x1 + ((size_t)b * NREAL + gi) * DIM
                                           : x3 + ((size_t)b * NPAD + (gi - NREAL)) * DIM;
            As[r][lk] = pa[kc + lk] * invn1[b * NFULL + gi];
            const int gj = j0 + r;
            const float* pb = (gj < NREAL) ? x2 + ((size_t)b * NREAL + gj) * DIM
                                           : x4 + ((size_t)b * NPAD + (gj - NREAL)) * DIM;
            Bs[r][lk] = pb[kc + lk] * invn2[b * NFULL + gj];
        }
        __syncthreads();
        #pragma unroll
        for (int k = 0; k < 64; k += 4) {
            float4 av[4], bv[4];
            #pragma unroll
            for (int u = 0; u < 4; ++u) av[u] = *(const float4*)&As[ty + 16*u][k];
            #pragma unroll
            for (int u = 0; u < 4; ++u) bv[u] = *(const float4*)&Bs[tx + 16*u][k];
            #pragma unroll
            for (int u = 0; u < 4; ++u)
                #pragma unroll
                for (int v = 0; v < 4; ++v) {
                    acc[u][v] += av[u].x * bv[v].x;
                    acc[u][v] += av[u].y * bv[v].y;
                    acc[u][v] += av[u].z * bv[v].z;
                    acc[u][v] += av[u].w * bv[v].w;
                }
        }
    }
    float rpart[4] = {}, cpart[4] = {};
    const bool store = (i0 < NREAL) && (j0 < NREAL);
    #pragma unroll
    for (int u = 0; u < 4; ++u)
        #pragma unroll
        for (int v = 0; v < 4; ++v) {
            const float s = __expf(10.0f * acc[u][v]);
            rpart[u] += s;
            cpart[v] += s;
            if (store) {
                const int i = i0 + ty + 16*u, j = j0 + tx + 16*v;
                S[((size_t)b * NREAL + i) * NREAL + j] = s;
            }
        }
    #pragma unroll
    for (int u = 0; u < 4; ++u) atomicAdd(&rsh[ty + 16*u], rpart[u]);
    #pragma unroll
    for (int v = 0; v < 4; ++v) atomicAdd(&csh[tx + 16*v], cpart[v]);
    __syncthreads();
    if (t < 64) {
        atomicAdd(&rowsum[b * NFULL + i0 + t], rsh[t]);
        atomicAdd(&colsum[b * NFULL + j0 + t], csh[t]);
    }
}

__global__ __launch_bounds__(256) void hinge_kernel(
    const float* __restrict__ x3, const float* __restrict__ x4, float* __restrict__ out)
{
    const int b  = blockIdx.z;
    const int i0 = blockIdx.y * 64;
    const int j0 = blockIdx.x * 64;
    __shared__ float As[64][68];
    __shared__ float Bs[64][68];
    const int t = threadIdx.x;
    const int tx = t & 15, ty = t >> 4;
    float acc[4][4] = {};
    const int lk = t & 63, r4 = t >> 6;
    for (int kc = 0; kc < DIM; kc += 64) {
        __syncthreads();
        #pragma unroll
        for (int rr = 0; rr < 64; rr += 4) {
            const int r = rr + r4;
            As[r][lk] = x3[((size_t)b * NPAD + i0 + r) * DIM + kc + lk];
            Bs[r][lk] = x4[((size_t)b * NPAD + j0 + r) * DIM + kc + lk];
        }
        __syncthreads();
        #pragma unroll
        for (int k = 0; k < 64; k += 4) {
            float4 av[4], bv[4];
            #pragma unroll
            for (int u = 0; u < 4; ++u) av[u] = *(const float4*)&As[ty + 16*u][k];
            #pragma unroll
            for (int u = 0; u < 4; ++u) bv[u] = *(const float4*)&Bs[tx + 16*u][k];
            #pragma unroll
            for (int u = 0; u < 4; ++u)
                #pragma unroll
                for (int v = 0; v < 4; ++v) {
                    acc[u][v] += av[u].x * bv[v].x;
                    acc[u][v] += av[u].y * bv[v].y;
                    acc[u][v] += av[u].z * bv[v].z;
                    acc[u][v] += av[u].w * bv[v].w;
                }
        }
    }
    float part = 0.f;
    #pragma unroll
    for (int u = 0; u < 4; ++u)
        #pragma unroll
        for (int v = 0; v < 4; ++v) part += fmaxf(0.1f - acc[u][v], 0.f);
    __shared__ float red[256];
    red[t] = part;
    __syncthreads();
    for (int s = 128; s > 0; s >>= 1) { if (t < s) red[t] += red[t + s]; __syncthreads(); }
    if (t == 0) atomicAdd(out, red[0]);
}

// ---------------------------------------------------------------------------
extern "C" void kernel_launch(void* const* d_in, const int* in_sizes, int n_in,
                              void* d_out, int out_size, void* d_ws, size_t ws_size,
                              hipStream_t stream)
{
    const float* x1 = (const float*)d_in[0];
    const float* x2 = (const float*)d_in[1];
    const float* x3 = (const float*)d_in[2];
    const float* x4 = (const float*)d_in[3];
    float* out = (float*)d_out;

    char* p = (char*)d_ws;
    const size_t CBYTES = (size_t)BATCH * NREAL * NREAL * 4;  // 16.78 MB
    const size_t ABYTES = (size_t)BATCH * NFULL * 512 * 2;    // 14.68 MB
    const size_t NB = (size_t)BATCH * NFULL * 4;              // 57 KB
    const size_t PB = (size_t)BATCH * NREAL * 4;              // 32 KB
    const size_t FB = (size_t)BATCH * 64 * 4;                 // 4 KB flags
    const size_t SMALLB = 6 * NB + 4 * PB + FB;
    const bool mfma_ok = ws_size >= CBYTES + 2 * ABYTES + SMALLB;

    float* C = (float*)p; p += CBYTES;
    short* A1s = nullptr; short* B2s = nullptr;
    float* CT = nullptr;
    if (mfma_ok) {
        A1s = (short*)p; p += ABYTES;
        B2s = (short*)p; p += ABYTES;
        CT = (float*)A1s;   // A/B planes dead after gram; ST/CT reuses the region
    }
    float* rowsum = (float*)p; p += NB;
    float* colsum = (float*)p; p += NB;
    float* invn1  = (float*)p; p += NB;
    float* invn2  = (float*)p; p += NB;
    float* n1     = (float*)p; p += NB;
    float* n2     = (float*)p; p += NB;
    float* fs     = (float*)p; p += 2 * PB;
    float* gs     = (float*)p; p += 2 * PB;
    int*   flags  = (int*)p;  p += FB;
    if (!mfma_ok && ws_size >= (size_t)(p - (char*)d_ws) + CBYTES) {
        CT = (float*)p; p += CBYTES;
    }
    const int PS = BATCH * NREAL;

    int dev = 0;
    hipGetDevice(&dev);
    int coopAttr = 0;
    hipDeviceGetAttribute(&coopAttr, hipDeviceAttributeCooperativeLaunch, dev);
    int numCU = 0;
    hipDeviceGetAttribute(&numCU, hipDeviceAttributeMultiprocessorCount, dev);
    int maxB = 0;
    hipOccupancyMaxActiveBlocksPerMultiprocessor(
        &maxB, (const void*)sinkhorn_fused_kernel, 256, 0);
    const bool use_fused = mfma_ok && coopAttr && (maxB * numCU >= 512);

    if (mfma_ok) {
        norm_cvt_kernel<<<(2 * BATCH * NFULL) / 4, 256, 0, stream>>>(
            x1, x3, x2, x4, A1s, B2s, invn1, invn2, n1, n2, rowsum, out,
            use_fused ? flags : nullptr);
        gram_mfma_kernel<<<784, 256, 0, stream>>>(
            A1s, B2s, n1, n2, C, rowsum, colsum, out);
    } else {
        hipMemsetAsync(out, 0, 2 * sizeof(float), stream);
        hipMemsetAsync(rowsum, 0, 2 * NB, stream);
        norm_kernel<<<(2 * BATCH * NFULL) / 4, 256, 0, stream>>>(
            x1, x3, x2, x4, invn1, invn2);
        gram_kernel<<<dim3(14, 14, BATCH), 256, 0, stream>>>(
            x1, x3, x2, x4, invn1, invn2, C, rowsum, colsum);
        hinge_kernel<<<dim3(6, 6, BATCH), 256, 0, stream>>>(x3, x4, out);
    }

    if (use_fused) {
        // C holds raw S; transform folded into the fused kernel's reg load.
        void* args[] = {&C, &CT, &rowsum, &colsum, &fs, &gs, &out, &flags};
        hipLaunchCooperativeKernel((void*)sinkhorn_fused_kernel,
                                   dim3(512), dim3(256), args, 0, stream);
        return;
    }

    // fallback: separate cost + softmin chain (transforms C, writes CT)
    cost_kernel<<<dim3(8, 8, BATCH), 256, 0, stream>>>(C, CT, rowsum, colsum);
    const int SMB = 1024;
    const float epsl[8] = {9.0f, 9.0f, 2.25f, 0.5625f, 0.140625f,
                           0.03515625f, 0.0087890625f, 0.0025f};
    softmin_kernel<<<SMB, 256, 0, stream>>>(C, CT, fs, gs, fs, gs, 9.0f, 0, out);
    int cur = 0;
    for (int k = 0; k < 8; ++k) {
        softmin_kernel<<<SMB, 256, 0, stream>>>(C, CT,
            fs + cur * PS, gs + cur * PS,
            fs + (1 - cur) * PS, gs + (1 - cur) * PS,
            epsl[k], 1, out);
        cur ^= 1;
    }
    softmin_kernel<<<SMB, 256, 0, stream>>>(C, CT,
        fs + cur * PS, gs + cur * PS, nullptr, nullptr,
        0.0025f, 2, out + 1);
}

// Round 11
// 201.835 us; speedup vs baseline: 1.0107x; 1.0107x over previous
//
#include <hip/hip_runtime.h>
#include <cstddef>
#include <cstdint>

#define BATCH 16
#define NFULL 896   // 512 real + 384 pad
#define NREAL 512
#define NPAD  384
#define DIM   256

typedef short bf16x8 __attribute__((ext_vector_type(8)));
typedef short s16x4  __attribute__((ext_vector_type(4)));
typedef float f32x4  __attribute__((ext_vector_type(4)));

// round-to-nearest-even f32 -> bf16 bits (no NaN inputs here)
static __device__ inline short f2bf(float v) {
    unsigned u = __float_as_uint(v);
    unsigned r = (u + 0x7FFFu + ((u >> 16) & 1u)) >> 16;
    return (short)r;
}
static __device__ inline float bf2f(short s) {
    return __uint_as_float(((unsigned)(unsigned short)s) << 16);
}

// async global->LDS, 16B per lane. LDS dest = wave-uniform base + lane*16.
static __device__ __forceinline__ void gload_lds16(const void* g, size_t lds_byte_off,
                                                   void* lds_base) {
    __builtin_amdgcn_global_load_lds(
        (const __attribute__((address_space(1))) unsigned int*)(size_t)g,
        (__attribute__((address_space(3))) unsigned int*)(unsigned int)
            ((size_t)lds_base + lds_byte_off),
        16, 0, 0);
}

// ---------------------------------------------------------------------------
// One wave per row: norm, inv-norm, split-bf16 (hi|lo) planes of normalized row.
// Also zero-inits rowsum/colsum and out[0..1] (replaces memset nodes).
__global__ __launch_bounds__(256) void norm_cvt_kernel(
    const float* __restrict__ x1, const float* __restrict__ x3,
    const float* __restrict__ x2, const float* __restrict__ x4,
    short* __restrict__ A1s, short* __restrict__ B2s,
    float* __restrict__ invn1, float* __restrict__ invn2,
    float* __restrict__ n1, float* __restrict__ n2,
    float* __restrict__ zero_base, float* __restrict__ out)
{
    const int t = threadIdx.x;
    const int gid = blockIdx.x * 256 + t;
    if (gid < 2 * BATCH * NFULL) zero_base[gid] = 0.f;   // rowsum+colsum contiguous
    if (gid < 2) out[gid] = 0.f;

    const int w = t >> 6, lane = t & 63;
    const int rg = blockIdx.x * 4 + w;           // 0 .. 2*B*NFULL-1
    const int side = rg >= BATCH * NFULL;
    const int rem  = rg - (side ? BATCH * NFULL : 0);
    const int b = rem / NFULL, row = rem % NFULL;
    const float* src;
    if (!side) src = (row < NREAL) ? x1 + ((size_t)b * NREAL + row) * DIM
                                   : x3 + ((size_t)b * NPAD + (row - NREAL)) * DIM;
    else       src = (row < NREAL) ? x2 + ((size_t)b * NREAL + row) * DIM
                                   : x4 + ((size_t)b * NPAD + (row - NREAL)) * DIM;
    const f32x4 v = ((const f32x4*)src)[lane];
    float ss = v[0]*v[0] + v[1]*v[1] + v[2]*v[2] + v[3]*v[3];
    #pragma unroll
    for (int m = 1; m < 64; m <<= 1) ss += __shfl_xor(ss, m);
    const float nrm = sqrtf(ss);
    const float inv = 1.0f / fmaxf(nrm, 1e-12f);
    if (lane == 0) {
        (side ? invn2 : invn1)[b * NFULL + row] = inv;
        (side ? n2 : n1)[b * NFULL + row] = nrm;
    }
    s16x4 hi, lo;
    #pragma unroll
    for (int c = 0; c < 4; ++c) {
        const float val = v[c] * inv;
        hi[c] = f2bf(val);
        lo[c] = f2bf(val - bf2f(hi[c]));
    }
    short* dst = (side ? B2s : A1s) + ((size_t)b * NFULL + row) * 512;
    *(s16x4*)(dst + lane * 4) = hi;
    *(s16x4*)(dst + 256 + lane * 4) = lo;
}

// ---------------------------------------------------------------------------
// MFMA gram, split-bf16 K=768 (hi*hi + lo*hi + hi*lo), XCD-swizzled grid.
// NEW: BK=32 double-buffered pipeline. Per step: issue next-step loads into
// buf^1, counted s_waitcnt vmcnt(4) (current buf's 4 loads done; next's stay
// in flight ACROSS the raw s_barrier), 16 MFMA, raw barrier. LDS 32KB total
// -> 4 blocks/CU retained. Both-sides XOR swizzle (rule 21): linear LDS dest,
// inverse-swizzled global source, swizzled ds_read.
__global__ __launch_bounds__(256) void gram_mfma_kernel(
    const short* __restrict__ A1s, const short* __restrict__ B2s,
    const float* __restrict__ n1, const float* __restrict__ n2,
    float* __restrict__ S, float* __restrict__ rowsum, float* __restrict__ colsum,
    float* __restrict__ out_hinge)
{
    const int flat = blockIdx.x;                  // 784 = 8 XCD * 98
    const int id = (flat & 7) * 98 + (flat >> 3); // XCD k owns batches {2k,2k+1}
    const int b  = id / 49;
    const int r49 = id % 49;
    const int by = r49 / 7, bx = r49 % 7;
    const int i0 = by * 128;
    const int j0 = bx * 128;
    __shared__ __align__(16) short As[2][128][32];   // 2 x 8KB
    __shared__ __align__(16) short Bs[2][128][32];   // 2 x 8KB
    const int t = threadIdx.x;
    const int wid = t >> 6, lane = t & 63;
    const int wr = wid >> 1, wc = wid & 1;        // 2x2 waves, 64x64 each
    const int lr = lane & 15, lg = lane >> 4;
    f32x4 acc[4][4] = {};

    const short* gA = A1s + ((size_t)b * NFULL + i0) * 512;
    const short* gB = B2s + ((size_t)b * NFULL + j0) * 512;

    // staging slots: s = p*256 + t; row = s>>2; phys chunk = s&3;
    // logical chunk = (s&3) ^ (row&3)  (inverse-swizzled source)
    int srow[2], scl[2];
    #pragma unroll
    for (int p = 0; p < 2; ++p) {
        const int s = p * 256 + t;
        srow[p] = s >> 2;
        scl[p] = (s & 3) ^ (srow[p] & 3);
    }

    // 24 K-steps of 32; plane select: steps 8..15 use A-lo, 16..23 use B-lo.
    #define GRAM_ISSUE(step, buf)                                              \
        do {                                                                   \
            const int kb_   = (step) * 32;                                     \
            const int koff_ = kb_ & 255;                                       \
            const int aoff_ = (((kb_ >> 8) == 1) ? 256 : 0) + koff_;           \
            const int boff_ = (((kb_ >> 8) == 2) ? 256 : 0) + koff_;           \
            _Pragma("unroll")                                                  \
            for (int p = 0; p < 2; ++p)                                        \
                gload_lds16(gA + (size_t)srow[p] * 512 + aoff_ + scl[p] * 8,   \
                            (size_t)(p * 256 + wid * 64) * 16,                 \
                            &As[buf][0][0]);                                   \
            _Pragma("unroll")                                                  \
            for (int p = 0; p < 2; ++p)                                        \
                gload_lds16(gB + (size_t)srow[p] * 512 + boff_ + scl[p] * 8,   \
                            (size_t)(p * 256 + wid * 64) * 16,                 \
                            &Bs[buf][0][0]);                                   \
        } while (0)

    GRAM_ISSUE(0, 0);
    for (int step = 0; step < 24; ++step) {
        const int cur = step & 1;
        if (step + 1 < 24) {
            GRAM_ISSUE(step + 1, cur ^ 1);
            asm volatile("s_waitcnt vmcnt(4)" ::: "memory");  // cur's 4 done
        } else {
            asm volatile("s_waitcnt vmcnt(0)" ::: "memory");
        }
        __builtin_amdgcn_s_barrier();   // raw: next-step loads stay in flight
        bf16x8 af[4], bg[4];
        #pragma unroll
        for (int m = 0; m < 4; ++m) {
            const int row = wr * 64 + m * 16 + lr;
            af[m] = *(const bf16x8*)((const char*)&As[cur][0][0]
                     + row * 64 + (((lg) ^ (row & 3)) << 4));
        }
        #pragma unroll
        for (int n = 0; n < 4; ++n) {
            const int row = wc * 64 + n * 16 + lr;
            bg[n] = *(const bf16x8*)((const char*)&Bs[cur][0][0]
                     + row * 64 + (((lg) ^ (row & 3)) << 4));
        }
        #pragma unroll
        for (int m = 0; m < 4; ++m)
            #pragma unroll
            for (int n = 0; n < 4; ++n)
                acc[m][n] = __builtin_amdgcn_mfma_f32_16x16x32_bf16(
                    af[m], bg[n], acc[m][n], 0, 0, 0);
        __builtin_amdgcn_s_barrier();   // all reads of buf[cur] done
    }
    #undef GRAM_ISSUE

    const bool storeS = (by < 4) && (bx < 4);
    const bool hingeB = (by >= 4) && (bx >= 4);
    float rp[4][4] = {};
    float cp[4] = {};
    float hp = 0.f;
    #pragma unroll
    for (int m = 0; m < 4; ++m) {
        const int row0 = i0 + wr * 64 + m * 16 + lg * 4;
        float n1v[4] = {0.f, 0.f, 0.f, 0.f};
        if (hingeB) {
            #pragma unroll
            for (int r = 0; r < 4; ++r) n1v[r] = n1[b * NFULL + row0 + r];
        }
        #pragma unroll
        for (int n = 0; n < 4; ++n) {
            const int col = j0 + wc * 64 + n * 16 + lr;
            const f32x4 f = acc[m][n];
            float cn = 0.f;
            float sv[4];
            #pragma unroll
            for (int r = 0; r < 4; ++r) {
                sv[r] = __expf(10.f * f[r]);
                rp[m][r] += sv[r];
                cn += sv[r];
            }
            cp[n] += cn;
            if (storeS) {
                #pragma unroll
                for (int r = 0; r < 4; ++r)
                    S[((size_t)b * NREAL + row0 + r) * NREAL + col] = sv[r];
            }
            if (hingeB) {
                const float nn2 = n2[b * NFULL + col];
                #pragma unroll
                for (int r = 0; r < 4; ++r)
                    hp += fmaxf(0.1f - f[r] * n1v[r] * nn2, 0.f);
            }
        }
    }
    if (by < 4) {   // rowsum only read for real rows
        #pragma unroll
        for (int m = 0; m < 4; ++m)
            #pragma unroll
            for (int r = 0; r < 4; ++r) {
                float v = rp[m][r];
                v += __shfl_xor(v, 1); v += __shfl_xor(v, 2);
                v += __shfl_xor(v, 4); v += __shfl_xor(v, 8);
                if (lr == 0)
                    atomicAdd(&rowsum[b * NFULL + i0 + wr * 64 + m * 16 + lg * 4 + r], v);
            }
    }
    if (bx < 4) {   // colsum only read for real cols
        #pragma unroll
        for (int n = 0; n < 4; ++n) {
            float v = cp[n];
            v += __shfl_xor(v, 16); v += __shfl_xor(v, 32);
            if (lg == 0)
                atomicAdd(&colsum[b * NFULL + j0 + wc * 64 + n * 16 + lr], v);
        }
    }
    if (hingeB) {
        #pragma unroll
        for (int m = 1; m < 64; m <<= 1) hp += __shfl_xor(hp, m);
        if (lane == 0) atomicAdd(out_hinge, hp);
    }
}

// ---------------------------------------------------------------------------
// Cost transform + transpose, XCD-affine 1D grid (1024 blocks): xcd = blk&7
// owns batches {2*xcd, 2*xcd+1} -> C/CT slice (4 MB) lands in the local L2,
// warm for the softmin chain (same mapping there).
__global__ __launch_bounds__(256) void cost_kernel(
    float* __restrict__ C, float* __restrict__ CT,
    const float* __restrict__ rowsum, const float* __restrict__ colsum)
{
    const int blk = blockIdx.x;
    const int xcd = blk & 7, q = blk >> 3;
    const int b = 2 * xcd + (q >> 6);
    const int t64 = q & 63;
    const int i0 = (t64 >> 3) * 64, j0 = (t64 & 7) * 64;
    __shared__ float tile[64][65];
    const int t = threadIdx.x;
    const int lj = t & 63, r4 = t >> 6;
    #pragma unroll
    for (int rr = 0; rr < 64; rr += 4) {
        const int li = rr + r4;
        const size_t idx = ((size_t)b * NREAL + i0 + li) * NREAL + j0 + lj;
        const float s  = C[idx];
        const float c = 1.0f - s / (rowsum[b * NFULL + i0 + li]
                                    + colsum[b * NFULL + j0 + lj] - s);
        C[idx] = c;
        tile[li][lj] = c;
    }
    if (CT == nullptr) return;
    __syncthreads();
    #pragma unroll
    for (int rr = 0; rr < 64; rr += 4) {
        const int lc = rr + r4;
        CT[((size_t)b * NREAL + j0 + lc) * NREAL + i0 + lj] = tile[lj][lc];
    }
}

// ---------------------------------------------------------------------------
// Branchless two-pass softmin; one wave = 4 rows of one (side, b).
// XCD-affine mapping matches gram/cost: xcd = blk&7 -> batches {2k,2k+1},
// so all C/CT reads hit the owning XCD's L2.
// mode 0: write state. 1: 0.5*(old+new). 2: block-reduced atomicAdd(out).
__global__ __launch_bounds__(256) void softmin_kernel(
    const float* __restrict__ C, const float* __restrict__ CT,
    const float* __restrict__ f_in, const float* __restrict__ g_in,
    float* __restrict__ f_out, float* __restrict__ g_out,
    float eps, int mode, float* __restrict__ out)
{
    const int w = threadIdx.x >> 6, lane = threadIdx.x & 63;
    const int blk = blockIdx.x;                  // 1024
    const int xcd = blk & 7, q = blk >> 3;       // q 0..127
    const int b = 2 * xcd + (q >> 6);
    const int side = (q >> 5) & 1;
    const int ib = ((q & 31) * 4 + w) * 4;       // wave's first row
    const float inv_eps = 1.0f / eps;
    const float* h_src = (side ? f_in : g_in) + b * NREAL;

    f32x4 h0 = {0.f, 0.f, 0.f, 0.f}, h1 = h0;
    if (mode != 0) {
        const f32x4* h4 = (const f32x4*)h_src;
        h0 = h4[lane] * inv_eps;
        h1 = h4[64 + lane] * inv_eps;
    }
    const float* Mb;
    size_t stride;
    if (!side)   { Mb = C  + ((size_t)(b * NREAL + ib)) * NREAL; stride = 1; }
    else if (CT) { Mb = CT + ((size_t)(b * NREAL + ib)) * NREAL; stride = 1; }
    else         { Mb = C + (size_t)b * NREAL * NREAL + ib;      stride = NREAL; }

    float res[4];
    float acc_res = 0.f;
    #pragma unroll
    for (int rr = 0; rr < 4; ++rr) {
        float v[8];
        if (stride == 1) {
            const f32x4* M4 = (const f32x4*)(Mb + (size_t)rr * NREAL);
            const f32x4 a0 = M4[lane], a1 = M4[64 + lane];
            #pragma unroll
            for (int c = 0; c < 4; ++c) { v[c] = h0[c] - a0[c] * inv_eps;
                                          v[4+c] = h1[c] - a1[c] * inv_eps; }
        } else {
            const float* M = Mb + rr;
            #pragma unroll
            for (int qq = 0; qq < 8; ++qq) {
                const int j = (qq >> 2) * 256 + lane * 4 + (qq & 3);
                v[qq] = ((qq < 4) ? h0[qq & 3] : h1[qq & 3])
                        - M[(size_t)j * NREAL] * inv_eps;
            }
        }
        float mx = v[0];
        #pragma unroll
        for (int qq = 1; qq < 8; ++qq) mx = fmaxf(mx, v[qq]);
        #pragma unroll
        for (int off = 1; off < 64; off <<= 1) mx = fmaxf(mx, __shfl_xor(mx, off));
        float s = 0.f;
        #pragma unroll
        for (int qq = 0; qq < 8; ++qq) s += __expf(v[qq] - mx);
        #pragma unroll
        for (int off = 1; off < 64; off <<= 1) s += __shfl_xor(s, off);
        res[rr] = -eps * (mx + __logf(s));
        acc_res += res[rr];
    }
    if (mode == 2) {
        __shared__ float sred[4];
        if (lane == 0) sred[w] = acc_res;
        __syncthreads();
        if (threadIdx.x == 0)
            atomicAdd(out, (sred[0] + sred[1] + sred[2] + sred[3]) * (1.0f / BATCH));
    } else if (lane == 0) {
        float* st = (side ? g_out : f_out) + b * NREAL + ib;
        if (mode == 0) {
            *(f32x4*)st = f32x4{res[0], res[1], res[2], res[3]};
        } else {
            const f32x4 si = *(const f32x4*)((side ? g_in : f_in) + b * NREAL + ib);
            *(f32x4*)st = 0.5f * (si + f32x4{res[0], res[1], res[2], res[3]});
        }
    }
}

// ---------------------------------------------------------------------------
// fp32 fallback kernels (tiny-ws path only).
__global__ __launch_bounds__(256) void norm_kernel(
    const float* __restrict__ x1, const float* __restrict__ x3,
    const float* __restrict__ x2, const float* __restrict__ x4,
    float* __restrict__ invn1, float* __restrict__ invn2)
{
    const int w = threadIdx.x >> 6, lane = threadIdx.x & 63;
    const int rg = blockIdx.x * 4 + w;
    const int side = rg / (BATCH * NFULL);
    const int rem  = rg - side * (BATCH * NFULL);
    const int b = rem / NFULL, r = rem % NFULL;
    const float* src;
    if (side == 0)
        src = (r < NREAL) ? x1 + ((size_t)b * NREAL + r) * DIM
                          : x3 + ((size_t)b * NPAD + (r - NREAL)) * DIM;
    else
        src = (r < NREAL) ? x2 + ((size_t)b * NREAL + r) * DIM
                          : x4 + ((size_t)b * NPAD + (r - NREAL)) * DIM;
    float4 v = ((const float4*)src)[lane];
    float ss = v.x*v.x + v.y*v.y + v.z*v.z + v.w*v.w;
    #pragma unroll
    for (int m = 1; m < 64; m <<= 1) ss += __shfl_xor(ss, m);
    if (lane == 0)
        (side == 0 ? invn1 : invn2)[b * NFULL + r] = 1.0f / fmaxf(sqrtf(ss), 1e-12f);
}

__global__ __launch_bounds__(256) void gram_kernel(
    const float* __restrict__ x1, const float* __restrict__ x3,
    const float* __restrict__ x2, const float* __restrict__ x4,
    const float* __restrict__ invn1, const float* __restrict__ invn2,
    float* __restrict__ S, float* __restrict__ rowsum, float* __restrict__ colsum)
{
    const int b  = blockIdx.z;
    const int i0 = blockIdx.y * 64;
    const int j0 = blockIdx.x * 64;
    __shared__ float As[64][68];
    __shared__ float Bs[64][68];
    __shared__ float rsh[64], csh[64];
    const int t = threadIdx.x;
    const int tx = t & 15, ty = t >> 4;
    if (t < 64) { rsh[t] = 0.f; csh[t] = 0.f; }
    float acc[4][4] = {};
    const int lk = t & 63, r4 = t >> 6;
    for (int kc = 0; kc < DIM; kc += 64) {
        __syncthreads();
        #pragma unroll
        for (int rr = 0; rr < 64; rr += 4) {
            const int r = rr + r4;
            const int gi = i0 + r;
            const float* pa = (gi < NREAL) ? x1 + ((size_t)b * NREAL + gi) * DIM
                                           : x3 + ((size_t)b * NPAD + (gi - NREAL)) * DIM;
            As[r][lk] = pa[kc + lk] * invn1[b * NFULL + gi];
            const int gj = j0 + r;
            const float* pb = (gj < NREAL) ? x2 + ((size_t)b * NREAL + gj) * DIM
                                           : x4 + ((size_t)b * NPAD + (gj - NREAL)) * DIM;
            Bs[r][lk] = pb[kc + lk] * invn2[b * NFULL + gj];
        }
        __syncthreads();
        #pragma unroll
        for (int k = 0; k < 64; k += 4) {
            float4 av[4], bv[4];
            #pragma unroll
            for (int u = 0; u < 4; ++u) av[u] = *(const float4*)&As[ty + 16*u][k];
            #pragma unroll
            for (int u = 0; u < 4; ++u) bv[u] = *(const float4*)&Bs[tx + 16*u][k];
            #pragma unroll
            for (int u = 0; u < 4; ++u)
                #pragma unroll
                for (int v = 0; v < 4; ++v) {
                    acc[u][v] += av[u].x * bv[v].x;
                    acc[u][v] += av[u].y * bv[v].y;
                    acc[u][v] += av[u].z * bv[v].z;
                    acc[u][v] += av[u].w * bv[v].w;
                }
        }
    }
    float rpart[4] = {}, cpart[4] = {};
    const bool store = (i0 < NREAL) && (j0 < NREAL);
    #pragma unroll
    for (int u = 0; u < 4; ++u)
        #pragma unroll
        for (int v = 0; v < 4; ++v) {
            const float s = __expf(10.0f * acc[u][v]);
            rpart[u] += s;
            cpart[v] += s;
            if (store) {
                const int i = i0 + ty + 16*u, j = j0 + tx + 16*v;
                S[((size_t)b * NREAL + i) * NREAL + j] = s;
            }
        }
    #pragma unroll
    for (int u = 0; u < 4; ++u) atomicAdd(&rsh[ty + 16*u], rpart[u]);
    #pragma unroll
    for (int v = 0; v < 4; ++v) atomicAdd(&csh[tx + 16*v], cpart[v]);
    __syncthreads();
    if (t < 64) {
        atomicAdd(&rowsum[b * NFULL + i0 + t], rsh[t]);
        atomicAdd(&colsum[b * NFULL + j0 + t], csh[t]);
    }
}

__global__ __launch_bounds__(256) void hinge_kernel(
    const float* __restrict__ x3, const float* __restrict__ x4, float* __restrict__ out)
{
    const int b  = blockIdx.z;
    const int i0 = blockIdx.y * 64;
    const int j0 = blockIdx.x * 64;
    __shared__ float As[64][68];
    __shared__ float Bs[64][68];
    const int t = threadIdx.x;
    const int tx = t & 15, ty = t >> 4;
    float acc[4][4] = {};
    const int lk = t & 63, r4 = t >> 6;
    for (int kc = 0; kc < DIM; kc += 64) {
        __syncthreads();
        #pragma unroll
        for (int rr = 0; rr < 64; rr += 4) {
            const int r = rr + r4;
            As[r][lk] = x3[((size_t)b * NPAD + i0 + r) * DIM + kc + lk];
            Bs[r][lk] = x4[((size_t)b * NPAD + j0 + r) * DIM + kc + lk];
        }
        __syncthreads();
        #pragma unroll
        for (int k = 0; k < 64; k += 4) {
            float4 av[4], bv[4];
            #pragma unroll
            for (int u = 0; u < 4; ++u) av[u] = *(const float4*)&As[ty + 16*u][k];
            #pragma unroll
            for (int u = 0; u < 4; ++u) bv[u] = *(const float4*)&Bs[tx + 16*u][k];
            #pragma unroll
            for (int u = 0; u < 4; ++u)
                #pragma unroll
                for (int v = 0; v < 4; ++v) {
                    acc[u][v] += av[u].x * bv[v].x;
                    acc[u][v] += av[u].y * bv[v].y;
                    acc[u][v] += av[u].z * bv[v].z;
                    acc[u][v] += av[u].w * bv[v].w;
                }
        }
    }
    float part = 0.f;
    #pragma unroll
    for (int u = 0; u < 4; ++u)
        #pragma unroll
        for (int v = 0; v < 4; ++v) part += fmaxf(0.1f - acc[u][v], 0.f);
    __shared__ float red[256];
    red[t] = part;
    __syncthreads();
    for (int s = 128; s > 0; s >>= 1) { if (t < s) red[t] += red[t + s]; __syncthreads(); }
    if (t == 0) atomicAdd(out, red[0]);
}

// ---------------------------------------------------------------------------
extern "C" void kernel_launch(void* const* d_in, const int* in_sizes, int n_in,
                              void* d_out, int out_size, void* d_ws, size_t ws_size,
                              hipStream_t stream)
{
    const float* x1 = (const float*)d_in[0];
    const float* x2 = (const float*)d_in[1];
    const float* x3 = (const float*)d_in[2];
    const float* x4 = (const float*)d_in[3];
    float* out = (float*)d_out;

    char* p = (char*)d_ws;
    const size_t CBYTES = (size_t)BATCH * NREAL * NREAL * 4;  // 16.78 MB
    const size_t ABYTES = (size_t)BATCH * NFULL * 512 * 2;    // 14.68 MB
    const size_t NB = (size_t)BATCH * NFULL * 4;              // 57 KB
    const size_t PB = (size_t)BATCH * NREAL * 4;              // 32 KB
    const size_t SMALLB = 6 * NB + 4 * PB;
    const bool mfma_ok = ws_size >= CBYTES + 2 * ABYTES + SMALLB;

    float* C = (float*)p; p += CBYTES;
    short* A1s = nullptr; short* B2s = nullptr;
    float* CT = nullptr;
    if (mfma_ok) {
        A1s = (short*)p; p += ABYTES;
        B2s = (short*)p; p += ABYTES;
        CT = (float*)A1s;   // A/B planes dead after gram; CT reuses the region
    }
    float* rowsum = (float*)p; p += NB;
    float* colsum = (float*)p; p += NB;
    float* invn1  = (float*)p; p += NB;
    float* invn2  = (float*)p; p += NB;
    float* n1     = (float*)p; p += NB;
    float* n2     = (float*)p; p += NB;
    float* fs     = (float*)p; p += 2 * PB;
    float* gs     = (float*)p; p += 2 * PB;
    if (!mfma_ok && ws_size >= (size_t)(p - (char*)d_ws) + CBYTES) {
        CT = (float*)p; p += CBYTES;
    }
    const int PS = BATCH * NREAL;

    if (mfma_ok) {
        norm_cvt_kernel<<<(2 * BATCH * NFULL) / 4, 256, 0, stream>>>(
            x1, x3, x2, x4, A1s, B2s, invn1, invn2, n1, n2, rowsum, out);
        gram_mfma_kernel<<<784, 256, 0, stream>>>(
            A1s, B2s, n1, n2, C, rowsum, colsum, out);
    } else {
        hipMemsetAsync(out, 0, 2 * sizeof(float), stream);
        hipMemsetAsync(rowsum, 0, 2 * NB, stream);
        norm_kernel<<<(2 * BATCH * NFULL) / 4, 256, 0, stream>>>(
            x1, x3, x2, x4, invn1, invn2);
        gram_kernel<<<dim3(14, 14, BATCH), 256, 0, stream>>>(
            x1, x3, x2, x4, invn1, invn2, C, rowsum, colsum);
        hinge_kernel<<<dim3(6, 6, BATCH), 256, 0, stream>>>(x3, x4, out);
    }

    cost_kernel<<<1024, 256, 0, stream>>>(C, CT, rowsum, colsum);

    const float epsl[8] = {9.0f, 9.0f, 2.25f, 0.5625f, 0.140625f,
                           0.03515625f, 0.0087890625f, 0.0025f};
    softmin_kernel<<<1024, 256, 0, stream>>>(C, CT, fs, gs, fs, gs, 9.0f, 0, out);
    int cur = 0;
    for (int k = 0; k < 8; ++k) {
        softmin_kernel<<<1024, 256, 0, stream>>>(C, CT,
            fs + cur * PS, gs + cur * PS,
            fs + (1 - cur) * PS, gs + (1 - cur) * PS,
            epsl[k], 1, out);
        cur ^= 1;
    }
    softmin_kernel<<<1024, 256, 0, stream>>>(C, CT,
        fs + cur * PS, gs + cur * PS, nullptr, nullptr,
        0.0025f, 2, out + 1);
}